// Round 1
// baseline (907.685 us; speedup 1.0000x reference)
//
#include <hip/hip_runtime.h>
#include <cstdint>

#define B_ 4
#define H_ 16
#define S_ 2048
#define D_ 64

typedef _Float16 half4 __attribute__((ext_vector_type(4)));
typedef _Float16 half8 __attribute__((ext_vector_type(8)));
typedef float f32x16 __attribute__((ext_vector_type(16)));

// ---------- pre-kernels (FAST path) ----------

// q -> fp16 * 0.125 (fold temperature), k -> fp16
__global__ void cvt_qk_kernel(const float* __restrict__ q, const float* __restrict__ k,
                              _Float16* __restrict__ qh, _Float16* __restrict__ kh) {
    const int64_t N = (int64_t)B_ * H_ * S_ * D_;
    const int64_t step = (int64_t)gridDim.x * blockDim.x * 4;
    for (int64_t i = ((int64_t)blockIdx.x * blockDim.x + threadIdx.x) * 4; i < N; i += step) {
        float4 a = *reinterpret_cast<const float4*>(q + i);
        float4 b = *reinterpret_cast<const float4*>(k + i);
        half4 ah = { (_Float16)(a.x * 0.125f), (_Float16)(a.y * 0.125f),
                     (_Float16)(a.z * 0.125f), (_Float16)(a.w * 0.125f) };
        half4 bh = { (_Float16)b.x, (_Float16)b.y, (_Float16)b.z, (_Float16)b.w };
        *reinterpret_cast<half4*>(qh + i) = ah;
        *reinterpret_cast<half4*>(kh + i) = bh;
    }
}

// V [b,h,s,d] fp32 -> Vt [b,h,d,s] fp16
__global__ void transpose_v_kernel(const float* __restrict__ v, _Float16* __restrict__ vt) {
    const int bh = blockIdx.y;
    const int k0 = blockIdx.x * 64;
    const float* vp = v + (int64_t)bh * S_ * D_;
    _Float16* vtp = vt + (int64_t)bh * D_ * S_;
    const int t = threadIdx.x;
    const int d = t & 63;
    const int kc = t >> 6;
    _Float16 tmp[16];
#pragma unroll
    for (int j = 0; j < 16; ++j)
        tmp[j] = (_Float16)vp[(int64_t)(k0 + kc * 16 + j) * D_ + d];
    half8 a, b;
#pragma unroll
    for (int j = 0; j < 8; ++j) { a[j] = tmp[j]; b[j] = tmp[8 + j]; }
    half8* dst = reinterpret_cast<half8*>(vtp + (int64_t)d * S_ + k0 + kc * 16);
    dst[0] = a; dst[1] = b;
}

// mask int32 [b,q,k] -> bitmask, bit j of word (b,q,k0/32) = (mask[k0+j] != 0)
__global__ void pack_mask_kernel(const int* __restrict__ mask, uint32_t* __restrict__ mbits) {
    const int64_t groups = (int64_t)B_ * S_ * S_ / 64;
    const int lane = threadIdx.x & 63;
    const int64_t wstep = ((int64_t)gridDim.x * blockDim.x) >> 6;
    for (int64_t g = ((int64_t)blockIdx.x * blockDim.x + threadIdx.x) >> 6; g < groups; g += wstep) {
        int mv = mask[g * 64 + lane];
        unsigned long long bits = __ballot(mv != 0);
        if (lane == 0)
            *reinterpret_cast<unsigned long long*>(mbits + g * 2) = bits;
    }
}

// ---------- main attention kernel ----------
// grid (S/32, H, B), 256 threads (4 waves). Wave w handles keys (4i+w)*32, i=0..15.
// MFMA 32x32x16 f16: C/D col=lane&31, row=(r&3)+8*(r>>2)+4*(lane>>5).

template<bool FAST>
__global__ __launch_bounds__(256) void attn_main(
    const float* __restrict__ qf, const float* __restrict__ kf, const float* __restrict__ vf,
    const int* __restrict__ maskI,
    const _Float16* __restrict__ qh, const _Float16* __restrict__ kh, const _Float16* __restrict__ vt,
    const uint32_t* __restrict__ mbits,
    float* __restrict__ out, float* __restrict__ attn)
{
    const int tid = threadIdx.x;
    const int w = tid >> 6;
    const int lane = tid & 63;
    const int c = lane & 31;
    const int hi = lane >> 5;
    const int q0 = blockIdx.x * 32;
    const int64_t bh = (int64_t)blockIdx.z * H_ + blockIdx.y;
    const int64_t bq = (int64_t)blockIdx.z * S_ + q0;   // mask row base (no H dim)

    __shared__ _Float16 Plds[4][32][36];   // per-wave P tile, stride 36 halves (72B)
    __shared__ float MlS[4][32];
    __shared__ float LlS[4][32];
    __shared__ float Olds[32][64];

    // ---- Q fragments (A operand): lane holds Q[q0+c][kk*16 + hi*8 + j] ----
    half8 aq[4];
    if (FAST) {
        const _Float16* qp = qh + (bh * S_ + q0 + c) * D_ + hi * 8;
#pragma unroll
        for (int kk = 0; kk < 4; ++kk)
            aq[kk] = *reinterpret_cast<const half8*>(qp + kk * 16);
    } else {
        const float* qp = qf + (bh * S_ + q0 + c) * D_ + hi * 8;
#pragma unroll
        for (int kk = 0; kk < 4; ++kk) {
#pragma unroll
            for (int j = 0; j < 8; ++j)
                aq[kk][j] = (_Float16)(qp[kk * 16 + j] * 0.125f);
        }
    }

    float mreg[16], lreg[16];
#pragma unroll
    for (int r = 0; r < 16; ++r) { mreg[r] = -1e30f; lreg[r] = 0.f; }

    // ================= Pass A: online row max / sum =================
    for (int it = 0; it < 16; ++it) {
        const int k0 = (it * 4 + w) * 32;
        f32x16 acc;
#pragma unroll
        for (int r = 0; r < 16; ++r) acc[r] = 0.f;
        if (FAST) {
            const _Float16* kp = kh + (bh * S_ + k0 + c) * D_ + hi * 8;
#pragma unroll
            for (int kk = 0; kk < 4; ++kk) {
                half8 bk = *reinterpret_cast<const half8*>(kp + kk * 16);
                acc = __builtin_amdgcn_mfma_f32_32x32x16_f16(aq[kk], bk, acc, 0, 0, 0);
            }
        } else {
            const float* kp = kf + (bh * S_ + k0 + c) * D_ + hi * 8;
#pragma unroll
            for (int kk = 0; kk < 4; ++kk) {
                half8 bk;
#pragma unroll
                for (int j = 0; j < 8; ++j) bk[j] = (_Float16)kp[kk * 16 + j];
                acc = __builtin_amdgcn_mfma_f32_32x32x16_f16(aq[kk], bk, acc, 0, 0, 0);
            }
        }
#pragma unroll
        for (int r = 0; r < 16; ++r) {
            const int row = (r & 3) + 8 * (r >> 2) + 4 * hi;
            float s = acc[r];
            bool dead;
            if (FAST) {
                uint32_t wv = mbits[(bq + row) * (S_ / 32) + (k0 >> 5)];
                dead = ((wv >> c) & 1u) == 0u;
            } else {
                dead = (maskI[(bq + row) * S_ + k0 + c] == 0);
            }
            s = dead ? -1e30f : s;
            float mo = mreg[r];
            float d = s - mo;
            float e = __expf(-fabsf(d));      // one exp per element
            bool le = (d <= 0.f);
            lreg[r] = le ? (lreg[r] + e) : fmaf(lreg[r], e, 1.0f);
            mreg[r] = le ? mo : s;
        }
    }

    // butterfly (m,l) reduce across the 32 lanes of each hi-group
#pragma unroll
    for (int r = 0; r < 16; ++r) {
        float m = mreg[r], l = lreg[r];
#pragma unroll
        for (int st = 1; st <= 16; st <<= 1) {
            float om = __shfl_xor(m, st, 64);
            float ol = __shfl_xor(l, st, 64);
            float mn = fmaxf(m, om);
            l = l * __expf(m - mn) + ol * __expf(om - mn);
            m = mn;
        }
        mreg[r] = m; lreg[r] = l;
    }

    // cross-wave combine via LDS
    if (c == 0) {
#pragma unroll
        for (int r = 0; r < 16; ++r) {
            const int row = (r & 3) + 8 * (r >> 2) + 4 * hi;
            MlS[w][row] = mreg[r];
            LlS[w][row] = lreg[r];
        }
    }
    __syncthreads();
#pragma unroll
    for (int r = 0; r < 16; ++r) {
        const int row = (r & 3) + 8 * (r >> 2) + 4 * hi;
        float m = -1e30f, l = 0.f;
#pragma unroll
        for (int ww = 0; ww < 4; ++ww) {
            float om = MlS[ww][row], ol = LlS[ww][row];
            float mn = fmaxf(m, om);
            l = l * __expf(m - mn) + ol * __expf(om - mn);
            m = mn;
        }
        mreg[r] = m;
        lreg[r] = 1.0f / l;    // reciprocal of denominator
    }

    // ================= Pass B: recompute S, write attn, PV =================
    f32x16 o0, o1;
#pragma unroll
    for (int r = 0; r < 16; ++r) { o0[r] = 0.f; o1[r] = 0.f; }

    for (int it = 0; it < 16; ++it) {
        const int k0 = (it * 4 + w) * 32;
        f32x16 acc;
#pragma unroll
        for (int r = 0; r < 16; ++r) acc[r] = 0.f;
        if (FAST) {
            const _Float16* kp = kh + (bh * S_ + k0 + c) * D_ + hi * 8;
#pragma unroll
            for (int kk = 0; kk < 4; ++kk) {
                half8 bk = *reinterpret_cast<const half8*>(kp + kk * 16);
                acc = __builtin_amdgcn_mfma_f32_32x32x16_f16(aq[kk], bk, acc, 0, 0, 0);
            }
        } else {
            const float* kp = kf + (bh * S_ + k0 + c) * D_ + hi * 8;
#pragma unroll
            for (int kk = 0; kk < 4; ++kk) {
                half8 bk;
#pragma unroll
                for (int j = 0; j < 8; ++j) bk[j] = (_Float16)kp[kk * 16 + j];
                acc = __builtin_amdgcn_mfma_f32_32x32x16_f16(aq[kk], bk, acc, 0, 0, 0);
            }
        }

        float* attnBase = attn + (bh * S_ + q0) * (int64_t)S_ + k0 + c;
#pragma unroll
        for (int r = 0; r < 16; ++r) {
            const int row = (r & 3) + 8 * (r >> 2) + 4 * hi;
            float s = acc[r];
            bool dead;
            if (FAST) {
                uint32_t wv = mbits[(bq + row) * (S_ / 32) + (k0 >> 5)];
                dead = ((wv >> c) & 1u) == 0u;
            } else {
                dead = (maskI[(bq + row) * S_ + k0 + c] == 0);
            }
            float p = dead ? 0.f : __expf(s - mreg[r]) * lreg[r];
            attnBase[(int64_t)row * S_] = p;          // coalesced 128B per half-wave
            Plds[w][row][c] = (_Float16)p;            // stage for PV A-fragment
        }
        __syncthreads();

#pragma unroll
        for (int kk = 0; kk < 2; ++kk) {
            // A-frag: P[q=c][key = kk*16 + hi*8 + j]
            const _Float16* pp = &Plds[w][c][kk * 16 + hi * 8];
            half4 p0lo = *reinterpret_cast<const half4*>(pp);
            half4 p0hi = *reinterpret_cast<const half4*>(pp + 4);
            half8 pa = __builtin_shufflevector(p0lo, p0hi, 0, 1, 2, 3, 4, 5, 6, 7);
            if (FAST) {
                const _Float16* vp = vt + (bh * D_ + c) * S_ + k0 + kk * 16 + hi * 8;
                half8 bv0 = *reinterpret_cast<const half8*>(vp);
                half8 bv1 = *reinterpret_cast<const half8*>(vp + 32 * S_);
                o0 = __builtin_amdgcn_mfma_f32_32x32x16_f16(pa, bv0, o0, 0, 0, 0);
                o1 = __builtin_amdgcn_mfma_f32_32x32x16_f16(pa, bv1, o1, 0, 0, 0);
            } else {
                const float* vp = vf + (bh * S_ + k0 + kk * 16 + hi * 8) * D_ + c;
                half8 bv0, bv1;
#pragma unroll
                for (int j = 0; j < 8; ++j) {
                    bv0[j] = (_Float16)vp[j * D_];
                    bv1[j] = (_Float16)vp[j * D_ + 32];
                }
                o0 = __builtin_amdgcn_mfma_f32_32x32x16_f16(pa, bv0, o0, 0, 0, 0);
                o1 = __builtin_amdgcn_mfma_f32_32x32x16_f16(pa, bv1, o1, 0, 0, 0);
            }
        }
    }

    // ---- combine O across the 4 waves (each covered disjoint keys) ----
    float* oz = &Olds[0][0];
#pragma unroll
    for (int j = 0; j < 8; ++j) oz[tid + 256 * j] = 0.f;
    __syncthreads();
#pragma unroll
    for (int r = 0; r < 16; ++r) {
        const int row = (r & 3) + 8 * (r >> 2) + 4 * hi;
        atomicAdd(&Olds[row][c], o0[r]);
        atomicAdd(&Olds[row][c + 32], o1[r]);
    }
    __syncthreads();
    {
        const int row = tid >> 3;
        const int d0 = (tid & 7) * 8;
        float* op = out + (bh * S_ + q0 + row) * D_ + d0;
#pragma unroll
        for (int j = 0; j < 8; ++j) op[j] = Olds[row][d0 + j];
    }
}

// ---------- launch ----------
extern "C" void kernel_launch(void* const* d_in, const int* in_sizes, int n_in,
                              void* d_out, int out_size, void* d_ws, size_t ws_size,
                              hipStream_t stream) {
    const float* q = (const float*)d_in[0];
    const float* k = (const float*)d_in[1];
    const float* v = (const float*)d_in[2];
    const int* mask = (const int*)d_in[3];
    float* out = (float*)d_out;
    float* attn = out + (int64_t)B_ * H_ * S_ * D_;

    const size_t nElem = (size_t)B_ * H_ * S_ * D_;           // 8388608
    const size_t maskWords = (size_t)B_ * S_ * (S_ / 32);     // 524288
    const size_t need = nElem * 2 * 3 + maskWords * 4;        // 52,428,800 B

    dim3 grid(S_ / 32, H_, B_);
    if (d_ws != nullptr && ws_size >= need) {
        _Float16* qh = (_Float16*)d_ws;
        _Float16* kh = qh + nElem;
        _Float16* vt = kh + nElem;
        uint32_t* mb = (uint32_t*)(vt + nElem);
        cvt_qk_kernel<<<2048, 256, 0, stream>>>(q, k, qh, kh);
        transpose_v_kernel<<<dim3(S_ / 64, B_ * H_), 256, 0, stream>>>(v, vt);
        pack_mask_kernel<<<2048, 256, 0, stream>>>(mask, mb);
        attn_main<true><<<grid, 256, 0, stream>>>(q, k, v, mask, qh, kh, vt, mb, out, attn);
    } else {
        attn_main<false><<<grid, 256, 0, stream>>>(q, k, v, mask,
                                                   nullptr, nullptr, nullptr, nullptr, out, attn);
    }
}

// Round 3
// 768.809 us; speedup vs baseline: 1.1806x; 1.1806x over previous
//
#include <hip/hip_runtime.h>
#include <cstdint>

#define B_ 4
#define H_ 16
#define S_ 2048
#define D_ 64

typedef _Float16 half4 __attribute__((ext_vector_type(4)));
typedef _Float16 half8 __attribute__((ext_vector_type(8)));
typedef float f32x4 __attribute__((ext_vector_type(4)));
typedef float f32x16 __attribute__((ext_vector_type(16)));

// ---------- pre-kernels (FAST path) ----------

// q -> fp16 * 0.125 (fold temperature), k -> fp16
__global__ void cvt_qk_kernel(const float* __restrict__ q, const float* __restrict__ k,
                              _Float16* __restrict__ qh, _Float16* __restrict__ kh) {
    const int64_t N = (int64_t)B_ * H_ * S_ * D_;
    const int64_t step = (int64_t)gridDim.x * blockDim.x * 4;
    for (int64_t i = ((int64_t)blockIdx.x * blockDim.x + threadIdx.x) * 4; i < N; i += step) {
        float4 a = *reinterpret_cast<const float4*>(q + i);
        float4 b = *reinterpret_cast<const float4*>(k + i);
        half4 ah = { (_Float16)(a.x * 0.125f), (_Float16)(a.y * 0.125f),
                     (_Float16)(a.z * 0.125f), (_Float16)(a.w * 0.125f) };
        half4 bh = { (_Float16)b.x, (_Float16)b.y, (_Float16)b.z, (_Float16)b.w };
        *reinterpret_cast<half4*>(qh + i) = ah;
        *reinterpret_cast<half4*>(kh + i) = bh;
    }
}

// V [b,h,s,d] fp32 -> Vt [b,h,d,s] fp16
__global__ void transpose_v_kernel(const float* __restrict__ v, _Float16* __restrict__ vt) {
    const int bh = blockIdx.y;
    const int k0 = blockIdx.x * 64;
    const float* vp = v + (int64_t)bh * S_ * D_;
    _Float16* vtp = vt + (int64_t)bh * D_ * S_;
    const int t = threadIdx.x;
    const int d = t & 63;
    const int kc = t >> 6;
    _Float16 tmp[16];
#pragma unroll
    for (int j = 0; j < 16; ++j)
        tmp[j] = (_Float16)vp[(int64_t)(k0 + kc * 16 + j) * D_ + d];
    half8 a, b;
#pragma unroll
    for (int j = 0; j < 8; ++j) { a[j] = tmp[j]; b[j] = tmp[8 + j]; }
    half8* dst = reinterpret_cast<half8*>(vtp + (int64_t)d * S_ + k0 + kc * 16);
    dst[0] = a; dst[1] = b;
}

// mask int32 [b,q,k] -> bitmask, bit j of word (b,q,k0/32) = (mask[k0+j] != 0)
__global__ void pack_mask_kernel(const int* __restrict__ mask, uint32_t* __restrict__ mbits) {
    const int64_t groups = (int64_t)B_ * S_ * S_ / 64;
    const int lane = threadIdx.x & 63;
    const int64_t wstep = ((int64_t)gridDim.x * blockDim.x) >> 6;
    for (int64_t g = ((int64_t)blockIdx.x * blockDim.x + threadIdx.x) >> 6; g < groups; g += wstep) {
        int mv = mask[g * 64 + lane];
        unsigned long long bits = __ballot(mv != 0);
        if (lane == 0)
            *reinterpret_cast<unsigned long long*>(mbits + g * 2) = bits;
    }
}

// ---------- main attention kernel ----------
// grid (S/32, H, B), 256 threads (4 waves). Wave w handles keys (4i+w)*32, i=0..15.
// MFMA 32x32x16 f16: C/D col=lane&31 (key), row=(r&3)+8*(r>>2)+4*(lane>>5) (query).
// NO per-iteration __syncthreads: Plds is strictly per-wave; compiler-inserted
// lgkmcnt covers the write->read dependency; attn stores stay in flight.

template<bool FAST>
__global__ __launch_bounds__(256) void attn_main(
    const float* __restrict__ qf, const float* __restrict__ kf, const float* __restrict__ vf,
    const int* __restrict__ maskI,
    const _Float16* __restrict__ qh, const _Float16* __restrict__ kh, const _Float16* __restrict__ vt,
    const uint32_t* __restrict__ mbits,
    float* __restrict__ out, float* __restrict__ attn)
{
    const int tid = threadIdx.x;
    const int w = tid >> 6;
    const int lane = tid & 63;
    const int c = lane & 31;
    const int hi = lane >> 5;
    const int q0 = blockIdx.x * 32;
    const int64_t bh = (int64_t)blockIdx.z * H_ + blockIdx.y;
    const int64_t bq = (int64_t)blockIdx.z * S_ + q0;   // mask row base (no H dim)

    __shared__ _Float16 Plds[4][32][36];   // per-wave P tile, stride 36 halves (72B)
    __shared__ uint32_t Mw[32][64];        // mask bits for 32 q-rows x 2048 keys (8KB)
    __shared__ float MlS[4][32];
    __shared__ float LlS[4][32];
    __shared__ float Olds[32][64];

    // ---- stage mask bits into LDS (reused 2 passes x 16 iters x 16 rows) ----
    if (FAST) {
#pragma unroll
        for (int g = tid; g < 32 * 64; g += 256) {
            const int row = g >> 6, wc = g & 63;
            Mw[row][wc] = mbits[(bq + row) * (S_ / 32) + wc];
        }
    } else {
        for (int g = w; g < 1024; g += 4) {           // 1024 groups of 64 ints
            const int row = g >> 5, pr = g & 31;
            int mv = maskI[(bq + row) * (int64_t)S_ + pr * 64 + lane];
            unsigned long long bits = __ballot(mv != 0);
            if (lane == 0) {
                Mw[row][pr * 2]     = (uint32_t)bits;
                Mw[row][pr * 2 + 1] = (uint32_t)(bits >> 32);
            }
        }
    }

    // ---- Q fragments (A operand): lane holds Q[q0+c][kk*16 + hi*8 + j] ----
    half8 aq[4];
    if (FAST) {
        const _Float16* qp = qh + (bh * S_ + q0 + c) * D_ + hi * 8;
#pragma unroll
        for (int kk = 0; kk < 4; ++kk)
            aq[kk] = *reinterpret_cast<const half8*>(qp + kk * 16);
    } else {
        const float* qp = qf + (bh * S_ + q0 + c) * D_ + hi * 8;
#pragma unroll
        for (int kk = 0; kk < 4; ++kk) {
#pragma unroll
            for (int j = 0; j < 8; ++j)
                aq[kk][j] = (_Float16)(qp[kk * 16 + j] * 0.125f);
        }
    }

    __syncthreads();   // mask staging visible to all waves

    float mreg[16], lreg[16];
#pragma unroll
    for (int r = 0; r < 16; ++r) { mreg[r] = -1e30f; lreg[r] = 0.f; }

    // ================= Pass A: online row max / sum =================
    for (int it = 0; it < 16; ++it) {
        const int k0 = (it * 4 + w) * 32;
        const int widx = k0 >> 5;
        f32x16 acc;
#pragma unroll
        for (int r = 0; r < 16; ++r) acc[r] = 0.f;
        if (FAST) {
            const _Float16* kp = kh + (bh * S_ + k0 + c) * D_ + hi * 8;
#pragma unroll
            for (int kk = 0; kk < 4; ++kk) {
                half8 bk = *reinterpret_cast<const half8*>(kp + kk * 16);
                acc = __builtin_amdgcn_mfma_f32_32x32x16_f16(aq[kk], bk, acc, 0, 0, 0);
            }
        } else {
            const float* kp = kf + (bh * S_ + k0 + c) * D_ + hi * 8;
#pragma unroll
            for (int kk = 0; kk < 4; ++kk) {
                half8 bk;
#pragma unroll
                for (int j = 0; j < 8; ++j) bk[j] = (_Float16)kp[kk * 16 + j];
                acc = __builtin_amdgcn_mfma_f32_32x32x16_f16(aq[kk], bk, acc, 0, 0, 0);
            }
        }
#pragma unroll
        for (int r = 0; r < 16; ++r) {
            const int row = (r & 3) + 8 * (r >> 2) + 4 * hi;
            float s = acc[r];
            const uint32_t wv = Mw[row][widx];
            const bool dead = ((wv >> c) & 1u) == 0u;
            s = dead ? -1e30f : s;
            float mo = mreg[r];
            float d = s - mo;
            float e = __expf(-fabsf(d));      // one exp per element
            bool le = (d <= 0.f);
            lreg[r] = le ? (lreg[r] + e) : fmaf(lreg[r], e, 1.0f);
            mreg[r] = le ? mo : s;
        }
    }

    // butterfly (m,l) reduce across the 32 lanes of each hi-group
#pragma unroll
    for (int r = 0; r < 16; ++r) {
        float m = mreg[r], l = lreg[r];
#pragma unroll
        for (int st = 1; st <= 16; st <<= 1) {
            float om = __shfl_xor(m, st, 64);
            float ol = __shfl_xor(l, st, 64);
            float mn = fmaxf(m, om);
            l = l * __expf(m - mn) + ol * __expf(om - mn);
            m = mn;
        }
        mreg[r] = m; lreg[r] = l;
    }

    // cross-wave combine via LDS
    if (c == 0) {
#pragma unroll
        for (int r = 0; r < 16; ++r) {
            const int row = (r & 3) + 8 * (r >> 2) + 4 * hi;
            MlS[w][row] = mreg[r];
            LlS[w][row] = lreg[r];
        }
    }
    __syncthreads();
#pragma unroll
    for (int r = 0; r < 16; ++r) {
        const int row = (r & 3) + 8 * (r >> 2) + 4 * hi;
        float m = -1e30f, l = 0.f;
#pragma unroll
        for (int ww = 0; ww < 4; ++ww) {
            float om = MlS[ww][row], ol = LlS[ww][row];
            float mn = fmaxf(m, om);
            l = l * __expf(m - mn) + ol * __expf(om - mn);
            m = mn;
        }
        mreg[r] = m;
        lreg[r] = 1.0f / l;    // reciprocal of denominator
    }

    // ================= Pass B: recompute S, write attn, PV =================
    f32x16 o0, o1;
#pragma unroll
    for (int r = 0; r < 16; ++r) { o0[r] = 0.f; o1[r] = 0.f; }

    const int srow = lane >> 1;            // attn-store row handled by this lane
    const int cb = (lane & 1) * 4;         // col base (pairs give 32B contiguity)

    for (int it = 0; it < 16; ++it) {
        const int k0 = (it * 4 + w) * 32;
        const int widx = k0 >> 5;
        f32x16 acc;
#pragma unroll
        for (int r = 0; r < 16; ++r) acc[r] = 0.f;
        if (FAST) {
            const _Float16* kp = kh + (bh * S_ + k0 + c) * D_ + hi * 8;
#pragma unroll
            for (int kk = 0; kk < 4; ++kk) {
                half8 bk = *reinterpret_cast<const half8*>(kp + kk * 16);
                acc = __builtin_amdgcn_mfma_f32_32x32x16_f16(aq[kk], bk, acc, 0, 0, 0);
            }
        } else {
            const float* kp = kf + (bh * S_ + k0 + c) * D_ + hi * 8;
#pragma unroll
            for (int kk = 0; kk < 4; ++kk) {
                half8 bk;
#pragma unroll
                for (int j = 0; j < 8; ++j) bk[j] = (_Float16)kp[kk * 16 + j];
                acc = __builtin_amdgcn_mfma_f32_32x32x16_f16(aq[kk], bk, acc, 0, 0, 0);
            }
        }

#pragma unroll
        for (int r = 0; r < 16; ++r) {
            const int row = (r & 3) + 8 * (r >> 2) + 4 * hi;
            float s = acc[r];
            const uint32_t wv = Mw[row][widx];
            const bool dead = ((wv >> c) & 1u) == 0u;
            float p = dead ? 0.f : __expf(s - mreg[r]) * lreg[r];
            Plds[w][row][c] = (_Float16)p;            // stage (PV frag + attn store)
        }
        // (compiler inserts lgkmcnt wait: same-array LDS dependency)

        // ---- vectorized attn store from Plds: 4 x float4 per lane ----
        {
            float* abase = attn + ((bh * S_ + q0 + srow) * (int64_t)S_) + k0 + cb;
#pragma unroll
            for (int j = 0; j < 4; ++j) {
                half4 ph = *reinterpret_cast<const half4*>(&Plds[w][srow][cb + 8 * j]);
                f32x4 pf = { (float)ph[0], (float)ph[1], (float)ph[2], (float)ph[3] };
                __builtin_nontemporal_store(pf, reinterpret_cast<f32x4*>(abase + 8 * j));
            }
        }

#pragma unroll
        for (int kk = 0; kk < 2; ++kk) {
            // A-frag: P[q=c][key = kk*16 + hi*8 + j]
            const _Float16* pp = &Plds[w][c][kk * 16 + hi * 8];
            half4 p0lo = *reinterpret_cast<const half4*>(pp);
            half4 p0hi = *reinterpret_cast<const half4*>(pp + 4);
            half8 pa = __builtin_shufflevector(p0lo, p0hi, 0, 1, 2, 3, 4, 5, 6, 7);
            if (FAST) {
                const _Float16* vp = vt + (bh * D_ + c) * S_ + k0 + kk * 16 + hi * 8;
                half8 bv0 = *reinterpret_cast<const half8*>(vp);
                half8 bv1 = *reinterpret_cast<const half8*>(vp + 32 * S_);
                o0 = __builtin_amdgcn_mfma_f32_32x32x16_f16(pa, bv0, o0, 0, 0, 0);
                o1 = __builtin_amdgcn_mfma_f32_32x32x16_f16(pa, bv1, o1, 0, 0, 0);
            } else {
                const float* vp = vf + (bh * S_ + k0 + kk * 16 + hi * 8) * D_ + c;
                half8 bv0, bv1;
#pragma unroll
                for (int j = 0; j < 8; ++j) {
                    bv0[j] = (_Float16)vp[j * D_];
                    bv1[j] = (_Float16)vp[j * D_ + 32];
                }
                o0 = __builtin_amdgcn_mfma_f32_32x32x16_f16(pa, bv0, o0, 0, 0, 0);
                o1 = __builtin_amdgcn_mfma_f32_32x32x16_f16(pa, bv1, o1, 0, 0, 0);
            }
        }
    }

    // ---- combine O across the 4 waves (each covered disjoint keys) ----
    float* oz = &Olds[0][0];
#pragma unroll
    for (int j = 0; j < 8; ++j) oz[tid + 256 * j] = 0.f;
    __syncthreads();
#pragma unroll
    for (int r = 0; r < 16; ++r) {
        const int row = (r & 3) + 8 * (r >> 2) + 4 * hi;
        atomicAdd(&Olds[row][c], o0[r]);
        atomicAdd(&Olds[row][c + 32], o1[r]);
    }
    __syncthreads();
    {
        const int row = tid >> 3;
        const int d0 = (tid & 7) * 8;
        float* op = out + (bh * S_ + q0 + row) * D_ + d0;
#pragma unroll
        for (int j = 0; j < 8; ++j) op[j] = Olds[row][d0 + j];
    }
}

// ---------- launch ----------
extern "C" void kernel_launch(void* const* d_in, const int* in_sizes, int n_in,
                              void* d_out, int out_size, void* d_ws, size_t ws_size,
                              hipStream_t stream) {
    const float* q = (const float*)d_in[0];
    const float* k = (const float*)d_in[1];
    const float* v = (const float*)d_in[2];
    const int* mask = (const int*)d_in[3];
    float* out = (float*)d_out;
    float* attn = out + (int64_t)B_ * H_ * S_ * D_;

    const size_t nElem = (size_t)B_ * H_ * S_ * D_;           // 8388608
    const size_t maskWords = (size_t)B_ * S_ * (S_ / 32);     // 524288
    const size_t need = nElem * 2 * 3 + maskWords * 4;        // 52,428,800 B

    dim3 grid(S_ / 32, H_, B_);
    if (d_ws != nullptr && ws_size >= need) {
        _Float16* qh = (_Float16*)d_ws;
        _Float16* kh = qh + nElem;
        _Float16* vt = kh + nElem;
        uint32_t* mb = (uint32_t*)(vt + nElem);
        cvt_qk_kernel<<<2048, 256, 0, stream>>>(q, k, qh, kh);
        transpose_v_kernel<<<dim3(S_ / 64, B_ * H_), 256, 0, stream>>>(v, vt);
        pack_mask_kernel<<<2048, 256, 0, stream>>>(mask, mb);
        attn_main<true><<<grid, 256, 0, stream>>>(q, k, v, mask, qh, kh, vt, mb, out, attn);
    } else {
        attn_main<false><<<grid, 256, 0, stream>>>(q, k, v, mask,
                                                   nullptr, nullptr, nullptr, nullptr, out, attn);
    }
}

// Round 7
// 748.933 us; speedup vs baseline: 1.2120x; 1.0265x over previous
//
#include <hip/hip_runtime.h>
#include <cstdint>

#define B_ 4
#define H_ 16
#define S_ 2048
#define D_ 64

// fold temperature (1/8) and log2(e) into q so exp(x) == exp2(scaled dot)
#define QSCALE (0.125f * 1.44269504088896f)

typedef _Float16 half8 __attribute__((ext_vector_type(8)));
typedef float f32x4 __attribute__((ext_vector_type(4)));
typedef float f32x16 __attribute__((ext_vector_type(16)));
typedef uint32_t u32x2 __attribute__((ext_vector_type(2)));
typedef uint32_t u32x4 __attribute__((ext_vector_type(4)));

// ---------- pre-kernels (FAST path) ----------

__global__ void cvt_qk_kernel(const float* __restrict__ q, const float* __restrict__ k,
                              _Float16* __restrict__ qh, _Float16* __restrict__ kh) {
    const int64_t N = (int64_t)B_ * H_ * S_ * D_;
    const int64_t step = (int64_t)gridDim.x * blockDim.x * 4;
    for (int64_t i = ((int64_t)blockIdx.x * blockDim.x + threadIdx.x) * 4; i < N; i += step) {
        float4 a = *reinterpret_cast<const float4*>(q + i);
        float4 b = *reinterpret_cast<const float4*>(k + i);
        _Float16 ah[4] = { (_Float16)(a.x * QSCALE), (_Float16)(a.y * QSCALE),
                           (_Float16)(a.z * QSCALE), (_Float16)(a.w * QSCALE) };
        _Float16 bh[4] = { (_Float16)b.x, (_Float16)b.y, (_Float16)b.z, (_Float16)b.w };
        *reinterpret_cast<u32x2*>(qh + i) = *reinterpret_cast<u32x2*>(ah);
        *reinterpret_cast<u32x2*>(kh + i) = *reinterpret_cast<u32x2*>(bh);
    }
}

// V [b,h,s,d] fp32 -> Vt [b,h,d,s] fp16
__global__ void transpose_v_kernel(const float* __restrict__ v, _Float16* __restrict__ vt) {
    const int bh = blockIdx.y;
    const int k0 = blockIdx.x * 64;
    const float* vp = v + (int64_t)bh * S_ * D_;
    _Float16* vtp = vt + (int64_t)bh * D_ * S_;
    const int t = threadIdx.x;
    const int d = t & 63;
    const int kc = t >> 6;
    _Float16 tmp[16];
#pragma unroll
    for (int j = 0; j < 16; ++j)
        tmp[j] = (_Float16)vp[(int64_t)(k0 + kc * 16 + j) * D_ + d];
    half8 a, b;
#pragma unroll
    for (int j = 0; j < 8; ++j) { a[j] = tmp[j]; b[j] = tmp[8 + j]; }
    half8* dst = reinterpret_cast<half8*>(vtp + (int64_t)d * S_ + k0 + kc * 16);
    dst[0] = a; dst[1] = b;
}

// mask int32 [b,q,k] -> bitmask; bit (k%32) of word (b*S+q)*64 + k/32
__global__ void pack_mask_kernel(const int* __restrict__ mask, uint32_t* __restrict__ mbits) {
    const int64_t groups = (int64_t)B_ * S_ * S_ / 64;
    const int lane = threadIdx.x & 63;
    const int64_t wstep = ((int64_t)gridDim.x * blockDim.x) >> 6;
    for (int64_t g = ((int64_t)blockIdx.x * blockDim.x + threadIdx.x) >> 6; g < groups; g += wstep) {
        int mv = mask[g * 64 + lane];
        unsigned long long bits = __ballot(mv != 0);
        if (lane == 0)
            *reinterpret_cast<unsigned long long*>(mbits + g * 2) = bits;
    }
}

// ---------- main attention kernel ----------
// grid (S/128, H, B), 256 threads = 4 INDEPENDENT waves; wave w owns queries
// qw..qw+31 and iterates ALL 2048 keys. Swapped MFMA: acc = mfma(Kfrag, Qfrag)
// -> lane (c,hi) reg r holds S[key = k0 + (r&3)+8*(r>>2)+4*hi][query = qw+c],
// i.e. regs {4g..4g+3} are CONTIGUOUS keys {8g..8g+3}+4hi of query row qw+c.
// attn is stored DIRECTLY from registers (4 x f32x4 regular stores per tile;
// L2 merges the quads into full 64B lines). LDS holds the fp16 P tile only
// for the PV A-fragment (path validated by `out` correctness).

template<bool FAST>
__global__ __launch_bounds__(256, 4) void attn_main(
    const float* __restrict__ qf, const float* __restrict__ kf, const float* __restrict__ vf,
    const int* __restrict__ maskI,
    const _Float16* __restrict__ qh, const _Float16* __restrict__ kh, const _Float16* __restrict__ vt,
    const uint32_t* __restrict__ mbits,
    float* __restrict__ out, float* __restrict__ attn)
{
    const int tid = threadIdx.x;
    const int w = tid >> 6;
    const int lane = tid & 63;
    const int c = lane & 31;
    const int hi = lane >> 5;
    const int qw = blockIdx.x * 128 + w * 32;
    const int64_t bh = (int64_t)blockIdx.z * H_ + blockIdx.y;
    const int64_t qrow = (int64_t)blockIdx.z * S_ + qw + c;   // mask row for this lane

    __shared__ _Float16 Pl[4][32][36];    // per-wave P tile, stride 36 halves (72B, 8B-aligned rows)
    uint32_t* dwrow = reinterpret_cast<uint32_t*>(&Pl[w][c][0]);

    // ---- Q fragment (B operand): lane c holds Q[qw+c][kk*16 + hi*8 + j] ----
    half8 aq[4];
    if (FAST) {
        const _Float16* qp = qh + (bh * S_ + qw + c) * D_ + hi * 8;
#pragma unroll
        for (int kk = 0; kk < 4; ++kk)
            aq[kk] = *reinterpret_cast<const half8*>(qp + kk * 16);
    } else {
        const float* qp = qf + (bh * S_ + qw + c) * D_ + hi * 8;
#pragma unroll
        for (int kk = 0; kk < 4; ++kk)
#pragma unroll
            for (int j = 0; j < 8; ++j)
                aq[kk][j] = (_Float16)(qp[kk * 16 + j] * QSCALE);
    }

    const uint32_t* mrow = FAST ? (mbits + qrow * (S_ / 32)) : nullptr;

    // ================= Pass A: per-lane denominator =================
    float l = 0.f;
    for (int g = 0; g < 16; ++g) {
        u32x4 mq;
        if (FAST) mq = *reinterpret_cast<const u32x4*>(mrow + g * 4);
#pragma unroll
        for (int u = 0; u < 4; ++u) {
            const int k0 = (g * 4 + u) * 32;
            f32x16 acc;
#pragma unroll
            for (int r = 0; r < 16; ++r) acc[r] = 0.f;
            if (FAST) {
                const _Float16* kp = kh + (bh * S_ + k0 + c) * D_ + hi * 8;
#pragma unroll
                for (int kk = 0; kk < 4; ++kk) {
                    half8 bk = *reinterpret_cast<const half8*>(kp + kk * 16);
                    acc = __builtin_amdgcn_mfma_f32_32x32x16_f16(bk, aq[kk], acc, 0, 0, 0);
                }
            } else {
                const float* kp = kf + (bh * S_ + k0 + c) * D_ + hi * 8;
#pragma unroll
                for (int kk = 0; kk < 4; ++kk) {
                    half8 bk;
#pragma unroll
                    for (int j = 0; j < 8; ++j) bk[j] = (_Float16)kp[kk * 16 + j];
                    acc = __builtin_amdgcn_mfma_f32_32x32x16_f16(bk, aq[kk], acc, 0, 0, 0);
                }
            }
            uint32_t mw = 0;
            if (FAST) mw = mq[u] >> (hi * 4);
            float e[16];
#pragma unroll
            for (int r = 0; r < 16; ++r) {
                bool dead;
                if (FAST) {
                    dead = ((mw >> ((r & 3) + 8 * (r >> 2))) & 1u) == 0u;
                } else {
                    const int key = k0 + (r & 3) + 8 * (r >> 2) + 4 * hi;
                    dead = maskI[qrow * S_ + key] == 0;
                }
                e[r] = __builtin_exp2f(dead ? -1e30f : acc[r]);
            }
#pragma unroll
            for (int st = 1; st < 16; st <<= 1)
#pragma unroll
                for (int i = 0; i < 16; i += 2 * st) e[i] += e[i + st];
            l += e[0];
        }
    }
    const float lt = l + __shfl_xor(l, 32);
    const float rinv = 1.0f / lt;

    // ================= Pass B: recompute, normalize, store attn, PV =================
    f32x16 o0, o1;
#pragma unroll
    for (int r = 0; r < 16; ++r) { o0[r] = 0.f; o1[r] = 0.f; }

    for (int g = 0; g < 16; ++g) {
        u32x4 mq;
        if (FAST) mq = *reinterpret_cast<const u32x4*>(mrow + g * 4);
#pragma unroll
        for (int u = 0; u < 4; ++u) {
            const int k0 = (g * 4 + u) * 32;
            f32x16 acc;
#pragma unroll
            for (int r = 0; r < 16; ++r) acc[r] = 0.f;
            if (FAST) {
                const _Float16* kp = kh + (bh * S_ + k0 + c) * D_ + hi * 8;
#pragma unroll
                for (int kk = 0; kk < 4; ++kk) {
                    half8 bk = *reinterpret_cast<const half8*>(kp + kk * 16);
                    acc = __builtin_amdgcn_mfma_f32_32x32x16_f16(bk, aq[kk], acc, 0, 0, 0);
                }
            } else {
                const float* kp = kf + (bh * S_ + k0 + c) * D_ + hi * 8;
#pragma unroll
                for (int kk = 0; kk < 4; ++kk) {
                    half8 bk;
#pragma unroll
                    for (int j = 0; j < 8; ++j) bk[j] = (_Float16)kp[kk * 16 + j];
                    acc = __builtin_amdgcn_mfma_f32_32x32x16_f16(bk, aq[kk], acc, 0, 0, 0);
                }
            }
            uint32_t mw = 0;
            if (FAST) mw = mq[u] >> (hi * 4);

            // per quad-group g4: regs {4g4..4g4+3} = keys {8g4..8g4+3}+4hi of row qw+c
            float* arow = attn + (bh * S_ + qw + c) * (int64_t)S_ + k0 + 4 * hi;
            uint32_t pk[8];
#pragma unroll
            for (int g4 = 0; g4 < 4; ++g4) {
                f32x4 pq;
#pragma unroll
                for (int e2 = 0; e2 < 4; ++e2) {
                    const int r = g4 * 4 + e2;
                    bool dead;
                    if (FAST) {
                        dead = ((mw >> (8 * g4 + e2)) & 1u) == 0u;
                    } else {
                        const int key = k0 + e2 + 8 * g4 + 4 * hi;
                        dead = maskI[qrow * S_ + key] == 0;
                    }
                    pq[e2] = __builtin_exp2f(dead ? -1e30f : acc[r]) * rinv;
                }
                // direct attn store: f32x4, regular (cached) store -> L2 merges lines
                *reinterpret_cast<f32x4*>(arow + 8 * g4) = pq;
                // fp16 pairs for the PV fragment via LDS
                pk[2 * g4]     = __builtin_bit_cast(uint32_t, __builtin_amdgcn_cvt_pkrtz(pq[0], pq[1]));
                pk[2 * g4 + 1] = __builtin_bit_cast(uint32_t, __builtin_amdgcn_cvt_pkrtz(pq[2], pq[3]));
            }
            // LDS write: row c(=query), dword col = key/2: pair j2 -> cols j2*4 + hi*2 + {0,1}
#pragma unroll
            for (int j2 = 0; j2 < 4; ++j2) {
                u32x2 val = { pk[2 * j2], pk[2 * j2 + 1] };
                *reinterpret_cast<u32x2*>(dwrow + j2 * 4 + hi * 2) = val;
            }

            // ---- fence: this wave's P writes ordered before cross-lane PV reads ----
            __builtin_amdgcn_wave_barrier();
            asm volatile("s_waitcnt lgkmcnt(0)" ::: "memory");
            __builtin_amdgcn_sched_barrier(0);

            // PV: A-frag lane (c,hi) = P[c][kk*16 + hi*8 + j] read back from LDS
#pragma unroll
            for (int kk = 0; kk < 2; ++kk) {
                const uint32_t* rp = dwrow + kk * 8 + hi * 4;
                u32x2 a0 = *reinterpret_cast<const u32x2*>(rp);
                u32x2 a1 = *reinterpret_cast<const u32x2*>(rp + 2);
                u32x4 paw = { a0[0], a0[1], a1[0], a1[1] };
                half8 pa = __builtin_bit_cast(half8, paw);
                half8 bv0, bv1;
                if (FAST) {
                    const _Float16* vp = vt + (bh * D_ + c) * S_ + k0 + kk * 16 + hi * 8;
                    bv0 = *reinterpret_cast<const half8*>(vp);
                    bv1 = *reinterpret_cast<const half8*>(vp + 32 * S_);
                } else {
                    const float* vp = vf + (bh * S_ + k0 + kk * 16 + hi * 8) * D_ + c;
#pragma unroll
                    for (int j = 0; j < 8; ++j) {
                        bv0[j] = (_Float16)vp[j * D_];
                        bv1[j] = (_Float16)vp[j * D_ + 32];
                    }
                }
                o0 = __builtin_amdgcn_mfma_f32_32x32x16_f16(pa, bv0, o0, 0, 0, 0);
                o1 = __builtin_amdgcn_mfma_f32_32x32x16_f16(pa, bv1, o1, 0, 0, 0);
            }

            // ---- fence: keep next iteration's P writes after these reads ----
            __builtin_amdgcn_wave_barrier();
        }
    }

    // ---- out store: lane (c,hi) reg r -> out[qw + rowmap(r,hi)][c and c+32] ----
#pragma unroll
    for (int r = 0; r < 16; ++r) {
        const int row = (r & 3) + 8 * (r >> 2) + 4 * hi;
        float* op = out + (bh * S_ + qw + row) * D_;
        op[c] = o0[r];
        op[c + 32] = o1[r];
    }
}

// ---------- launch ----------
extern "C" void kernel_launch(void* const* d_in, const int* in_sizes, int n_in,
                              void* d_out, int out_size, void* d_ws, size_t ws_size,
                              hipStream_t stream) {
    const float* q = (const float*)d_in[0];
    const float* k = (const float*)d_in[1];
    const float* v = (const float*)d_in[2];
    const int* mask = (const int*)d_in[3];
    float* out = (float*)d_out;
    float* attn = out + (int64_t)B_ * H_ * S_ * D_;

    const size_t nElem = (size_t)B_ * H_ * S_ * D_;           // 8388608
    const size_t maskWords = (size_t)B_ * S_ * (S_ / 32);     // 524288
    const size_t need = nElem * 2 * 3 + maskWords * 4;        // 52,428,800 B

    dim3 grid(S_ / 128, H_, B_);
    if (d_ws != nullptr && ws_size >= need) {
        _Float16* qh = (_Float16*)d_ws;
        _Float16* kh = qh + nElem;
        _Float16* vt = kh + nElem;
        uint32_t* mb = (uint32_t*)(vt + nElem);
        cvt_qk_kernel<<<2048, 256, 0, stream>>>(q, k, qh, kh);
        transpose_v_kernel<<<dim3(S_ / 64, B_ * H_), 256, 0, stream>>>(v, vt);
        pack_mask_kernel<<<2048, 256, 0, stream>>>(mask, mb);
        attn_main<true><<<grid, 256, 0, stream>>>(q, k, v, mask, qh, kh, vt, mb, out, attn);
    } else {
        attn_main<false><<<grid, 256, 0, stream>>>(q, k, v, mask,
                                                   nullptr, nullptr, nullptr, nullptr, out, attn);
    }
}

// Round 8
// 719.875 us; speedup vs baseline: 1.2609x; 1.0404x over previous
//
#include <hip/hip_runtime.h>
#include <cstdint>

#define B_ 4
#define H_ 16
#define S_ 2048
#define D_ 64

// fold temperature (1/8) and log2(e) into q so exp(x) == exp2(scaled dot)
#define QSCALE (0.125f * 1.44269504088896f)

typedef _Float16 half8 __attribute__((ext_vector_type(8)));
typedef float f32x4 __attribute__((ext_vector_type(4)));
typedef float f32x16 __attribute__((ext_vector_type(16)));
typedef uint32_t u32x2 __attribute__((ext_vector_type(2)));
typedef uint32_t u32x4 __attribute__((ext_vector_type(4)));

// ---------- pre-kernels (FAST path) ----------

__global__ void cvt_qk_kernel(const float* __restrict__ q, const float* __restrict__ k,
                              _Float16* __restrict__ qh, _Float16* __restrict__ kh) {
    const int64_t N = (int64_t)B_ * H_ * S_ * D_;
    const int64_t step = (int64_t)gridDim.x * blockDim.x * 4;
    for (int64_t i = ((int64_t)blockIdx.x * blockDim.x + threadIdx.x) * 4; i < N; i += step) {
        float4 a = *reinterpret_cast<const float4*>(q + i);
        float4 b = *reinterpret_cast<const float4*>(k + i);
        _Float16 ah[4] = { (_Float16)(a.x * QSCALE), (_Float16)(a.y * QSCALE),
                           (_Float16)(a.z * QSCALE), (_Float16)(a.w * QSCALE) };
        _Float16 bh[4] = { (_Float16)b.x, (_Float16)b.y, (_Float16)b.z, (_Float16)b.w };
        *reinterpret_cast<u32x2*>(qh + i) = *reinterpret_cast<u32x2*>(ah);
        *reinterpret_cast<u32x2*>(kh + i) = *reinterpret_cast<u32x2*>(bh);
    }
}

// V [b,h,s,d] fp32 -> Vt [b,h,d,s] fp16
__global__ void transpose_v_kernel(const float* __restrict__ v, _Float16* __restrict__ vt) {
    const int bh = blockIdx.y;
    const int k0 = blockIdx.x * 64;
    const float* vp = v + (int64_t)bh * S_ * D_;
    _Float16* vtp = vt + (int64_t)bh * D_ * S_;
    const int t = threadIdx.x;
    const int d = t & 63;
    const int kc = t >> 6;
    _Float16 tmp[16];
#pragma unroll
    for (int j = 0; j < 16; ++j)
        tmp[j] = (_Float16)vp[(int64_t)(k0 + kc * 16 + j) * D_ + d];
    half8 a, b;
#pragma unroll
    for (int j = 0; j < 8; ++j) { a[j] = tmp[j]; b[j] = tmp[8 + j]; }
    half8* dst = reinterpret_cast<half8*>(vtp + (int64_t)d * S_ + k0 + kc * 16);
    dst[0] = a; dst[1] = b;
}

// mask int32 [b,q,k] -> bitmask; bit (k%32) of word (b*S+q)*64 + k/32
__global__ void pack_mask_kernel(const int* __restrict__ mask, uint32_t* __restrict__ mbits) {
    const int64_t groups = (int64_t)B_ * S_ * S_ / 64;
    const int lane = threadIdx.x & 63;
    const int64_t wstep = ((int64_t)gridDim.x * blockDim.x) >> 6;
    for (int64_t g = ((int64_t)blockIdx.x * blockDim.x + threadIdx.x) >> 6; g < groups; g += wstep) {
        int mv = mask[g * 64 + lane];
        unsigned long long bits = __ballot(mv != 0);
        if (lane == 0)
            *reinterpret_cast<unsigned long long*>(mbits + g * 2) = bits;
    }
}

// ---------- main attention kernel ----------
// grid (S/128, H, B), 256 threads = 4 INDEPENDENT waves; wave w owns queries
// qw..qw+31 and iterates ALL 2048 keys. Swapped MFMA: acc = mfma(Kfrag, Qfrag)
// -> lane (c,hi) reg r holds S[key = k0 + (r&3)+8*(r>>2)+4*hi][query = qw+c].
// attn stored directly from registers (4 x f32x4 per tile; L2 merges lines).
// PV A-fragment built IN REGISTERS via v_permlane32_swap_b32 (one swap fills
// the fragment word for BOTH hi-halves) -> no LDS, no fences, no barriers;
// the compiler is free to software-pipeline K loads across tiles.

template<bool FAST>
__global__ __launch_bounds__(256, 2) void attn_main(
    const float* __restrict__ qf, const float* __restrict__ kf, const float* __restrict__ vf,
    const int* __restrict__ maskI,
    const _Float16* __restrict__ qh, const _Float16* __restrict__ kh, const _Float16* __restrict__ vt,
    const uint32_t* __restrict__ mbits,
    float* __restrict__ out, float* __restrict__ attn)
{
    const int tid = threadIdx.x;
    const int w = tid >> 6;
    const int lane = tid & 63;
    const int c = lane & 31;
    const int hi = lane >> 5;
    const int qw = blockIdx.x * 128 + w * 32;
    const int64_t bh = (int64_t)blockIdx.z * H_ + blockIdx.y;
    const int64_t qrow = (int64_t)blockIdx.z * S_ + qw + c;   // mask row for this lane

    // ---- Q fragment (B operand): lane c holds Q[qw+c][kk*16 + hi*8 + j] ----
    half8 aq[4];
    if (FAST) {
        const _Float16* qp = qh + (bh * S_ + qw + c) * D_ + hi * 8;
#pragma unroll
        for (int kk = 0; kk < 4; ++kk)
            aq[kk] = *reinterpret_cast<const half8*>(qp + kk * 16);
    } else {
        const float* qp = qf + (bh * S_ + qw + c) * D_ + hi * 8;
#pragma unroll
        for (int kk = 0; kk < 4; ++kk)
#pragma unroll
            for (int j = 0; j < 8; ++j)
                aq[kk][j] = (_Float16)(qp[kk * 16 + j] * QSCALE);
    }

    const uint32_t* mrow = FAST ? (mbits + qrow * (S_ / 32)) : nullptr;

    // ================= Pass A: per-lane denominator =================
    float l = 0.f;
    for (int g = 0; g < 16; ++g) {
        u32x4 mq;
        if (FAST) mq = *reinterpret_cast<const u32x4*>(mrow + g * 4);
#pragma unroll
        for (int u = 0; u < 4; ++u) {
            const int k0 = (g * 4 + u) * 32;
            f32x16 acc;
#pragma unroll
            for (int r = 0; r < 16; ++r) acc[r] = 0.f;
            if (FAST) {
                const _Float16* kp = kh + (bh * S_ + k0 + c) * D_ + hi * 8;
#pragma unroll
                for (int kk = 0; kk < 4; ++kk) {
                    half8 bk = *reinterpret_cast<const half8*>(kp + kk * 16);
                    acc = __builtin_amdgcn_mfma_f32_32x32x16_f16(bk, aq[kk], acc, 0, 0, 0);
                }
            } else {
                const float* kp = kf + (bh * S_ + k0 + c) * D_ + hi * 8;
#pragma unroll
                for (int kk = 0; kk < 4; ++kk) {
                    half8 bk;
#pragma unroll
                    for (int j = 0; j < 8; ++j) bk[j] = (_Float16)kp[kk * 16 + j];
                    acc = __builtin_amdgcn_mfma_f32_32x32x16_f16(bk, aq[kk], acc, 0, 0, 0);
                }
            }
            uint32_t mw = 0;
            if (FAST) mw = mq[u] >> (hi * 4);
            float e[16];
#pragma unroll
            for (int r = 0; r < 16; ++r) {
                bool dead;
                if (FAST) {
                    dead = ((mw >> ((r & 3) + 8 * (r >> 2))) & 1u) == 0u;
                } else {
                    const int key = k0 + (r & 3) + 8 * (r >> 2) + 4 * hi;
                    dead = maskI[qrow * S_ + key] == 0;
                }
                e[r] = __builtin_exp2f(dead ? -1e30f : acc[r]);
            }
#pragma unroll
            for (int st = 1; st < 16; st <<= 1)
#pragma unroll
                for (int i = 0; i < 16; i += 2 * st) e[i] += e[i + st];
            l += e[0];
        }
    }
    const float lt = l + __shfl_xor(l, 32);
    const float rinv = 1.0f / lt;

    // ================= Pass B: recompute, normalize, store attn, PV =================
    f32x16 o0, o1;
#pragma unroll
    for (int r = 0; r < 16; ++r) { o0[r] = 0.f; o1[r] = 0.f; }

    for (int g = 0; g < 16; ++g) {
        u32x4 mq;
        if (FAST) mq = *reinterpret_cast<const u32x4*>(mrow + g * 4);
#pragma unroll
        for (int u = 0; u < 4; ++u) {
            const int k0 = (g * 4 + u) * 32;
            f32x16 acc;
#pragma unroll
            for (int r = 0; r < 16; ++r) acc[r] = 0.f;
            if (FAST) {
                const _Float16* kp = kh + (bh * S_ + k0 + c) * D_ + hi * 8;
#pragma unroll
                for (int kk = 0; kk < 4; ++kk) {
                    half8 bk = *reinterpret_cast<const half8*>(kp + kk * 16);
                    acc = __builtin_amdgcn_mfma_f32_32x32x16_f16(bk, aq[kk], acc, 0, 0, 0);
                }
            } else {
                const float* kp = kf + (bh * S_ + k0 + c) * D_ + hi * 8;
#pragma unroll
                for (int kk = 0; kk < 4; ++kk) {
                    half8 bk;
#pragma unroll
                    for (int j = 0; j < 8; ++j) bk[j] = (_Float16)kp[kk * 16 + j];
                    acc = __builtin_amdgcn_mfma_f32_32x32x16_f16(bk, aq[kk], acc, 0, 0, 0);
                }
            }
            uint32_t mw = 0;
            if (FAST) mw = mq[u] >> (hi * 4);

            // per quad-group g4: regs {4g4..4g4+3} = keys {8g4..8g4+3}+4hi of row qw+c
            float* arow = attn + (bh * S_ + qw + c) * (int64_t)S_ + k0 + 4 * hi;
            uint32_t pk[8];
#pragma unroll
            for (int g4 = 0; g4 < 4; ++g4) {
                f32x4 pq;
#pragma unroll
                for (int e2 = 0; e2 < 4; ++e2) {
                    const int r = g4 * 4 + e2;
                    bool dead;
                    if (FAST) {
                        dead = ((mw >> (8 * g4 + e2)) & 1u) == 0u;
                    } else {
                        const int key = k0 + e2 + 8 * g4 + 4 * hi;
                        dead = maskI[qrow * S_ + key] == 0;
                    }
                    pq[e2] = __builtin_exp2f(dead ? -1e30f : acc[r]) * rinv;
                }
                // direct attn store: f32x4 regular (cached) store -> L2 merges lines
                *reinterpret_cast<f32x4*>(arow + 8 * g4) = pq;
                // fp16 key-pair words: pk[2g4+t] = keys {8g4+4hi+2t, +1} of row qw+c
                pk[2 * g4]     = __builtin_bit_cast(uint32_t, __builtin_amdgcn_cvt_pkrtz(pq[0], pq[1]));
                pk[2 * g4 + 1] = __builtin_bit_cast(uint32_t, __builtin_amdgcn_cvt_pkrtz(pq[2], pq[3]));
            }

            // ---- PV A-frag in registers via permlane32_swap ----
            // swap(A,B): res0[c,0]=A(c,0)  res0[c,1]=B(c,0)  res1[c,0]=A(c,1)  res1[c,1]=B(c,1)
            // kk=0 frag words: w0,w2 from (pk0,pk2); w1,w3 from (pk1,pk3)
            // kk=1 frag words: w0,w2 from (pk4,pk6); w1,w3 from (pk5,pk7)
            u32x2 rA = __builtin_amdgcn_permlane32_swap(pk[0], pk[2], false, false);
            u32x2 rB = __builtin_amdgcn_permlane32_swap(pk[1], pk[3], false, false);
            u32x2 rC = __builtin_amdgcn_permlane32_swap(pk[4], pk[6], false, false);
            u32x2 rD = __builtin_amdgcn_permlane32_swap(pk[5], pk[7], false, false);
            u32x4 fa0 = { rA[0], rB[0], rA[1], rB[1] };
            u32x4 fa1 = { rC[0], rD[0], rC[1], rD[1] };
            half8 pa0 = __builtin_bit_cast(half8, fa0);
            half8 pa1 = __builtin_bit_cast(half8, fa1);

            half8 bv00, bv01, bv10, bv11;
            if (FAST) {
                const _Float16* vp = vt + (bh * D_ + c) * S_ + k0 + hi * 8;
                bv00 = *reinterpret_cast<const half8*>(vp);            // kk=0, d=c
                bv01 = *reinterpret_cast<const half8*>(vp + 32 * S_);  // kk=0, d=c+32
                bv10 = *reinterpret_cast<const half8*>(vp + 16);       // kk=1, d=c
                bv11 = *reinterpret_cast<const half8*>(vp + 16 + 32 * S_);
            } else {
                const float* vp0 = vf + (bh * S_ + k0 + hi * 8) * D_ + c;
                const float* vp1 = vp0 + 16 * D_;
#pragma unroll
                for (int j = 0; j < 8; ++j) {
                    bv00[j] = (_Float16)vp0[j * D_];
                    bv01[j] = (_Float16)vp0[j * D_ + 32];
                    bv10[j] = (_Float16)vp1[j * D_];
                    bv11[j] = (_Float16)vp1[j * D_ + 32];
                }
            }
            o0 = __builtin_amdgcn_mfma_f32_32x32x16_f16(pa0, bv00, o0, 0, 0, 0);
            o1 = __builtin_amdgcn_mfma_f32_32x32x16_f16(pa0, bv01, o1, 0, 0, 0);
            o0 = __builtin_amdgcn_mfma_f32_32x32x16_f16(pa1, bv10, o0, 0, 0, 0);
            o1 = __builtin_amdgcn_mfma_f32_32x32x16_f16(pa1, bv11, o1, 0, 0, 0);
        }
    }

    // ---- out store: lane (c,hi) reg r -> out[qw + rowmap(r,hi)][c and c+32] ----
#pragma unroll
    for (int r = 0; r < 16; ++r) {
        const int row = (r & 3) + 8 * (r >> 2) + 4 * hi;
        float* op = out + (bh * S_ + qw + row) * D_;
        op[c] = o0[r];
        op[c + 32] = o1[r];
    }
}

// ---------- launch ----------
extern "C" void kernel_launch(void* const* d_in, const int* in_sizes, int n_in,
                              void* d_out, int out_size, void* d_ws, size_t ws_size,
                              hipStream_t stream) {
    const float* q = (const float*)d_in[0];
    const float* k = (const float*)d_in[1];
    const float* v = (const float*)d_in[2];
    const int* mask = (const int*)d_in[3];
    float* out = (float*)d_out;
    float* attn = out + (int64_t)B_ * H_ * S_ * D_;

    const size_t nElem = (size_t)B_ * H_ * S_ * D_;           // 8388608
    const size_t maskWords = (size_t)B_ * S_ * (S_ / 32);     // 524288
    const size_t need = nElem * 2 * 3 + maskWords * 4;        // 52,428,800 B

    dim3 grid(S_ / 128, H_, B_);
    if (d_ws != nullptr && ws_size >= need) {
        _Float16* qh = (_Float16*)d_ws;
        _Float16* kh = qh + nElem;
        _Float16* vt = kh + nElem;
        uint32_t* mb = (uint32_t*)(vt + nElem);
        cvt_qk_kernel<<<2048, 256, 0, stream>>>(q, k, qh, kh);
        transpose_v_kernel<<<dim3(S_ / 64, B_ * H_), 256, 0, stream>>>(v, vt);
        pack_mask_kernel<<<2048, 256, 0, stream>>>(mask, mb);
        attn_main<true><<<grid, 256, 0, stream>>>(q, k, v, mask, qh, kh, vt, mb, out, attn);
    } else {
        attn_main<false><<<grid, 256, 0, stream>>>(q, k, v, mask,
                                                   nullptr, nullptr, nullptr, nullptr, out, attn);
    }
}